// Round 14
// baseline (343.629 us; speedup 1.0000x reference)
//
#include <hip/hip_runtime.h>
#include <hip/hip_bf16.h>
#include <hip/hip_fp16.h>
#include <stdint.h>

typedef __attribute__((ext_vector_type(8))) _Float16 f16x8;
typedef __attribute__((ext_vector_type(4))) float f32x4;

#define B_  32
#define S_  512
#define K_  512
#define H_  1024
#define HS  64           // h-cols per block
#define SC  128          // s-rows per chunk
#define NKT 16           // K_/32
#define NSC 4            // S_/SC

// LDS: x dbuf 2x8K | W dbuf 2x12K = 40KB -> 4 blocks/CU (160KB).
// 64B-row swizzle: logical 16B slot j of row r stored at j ^ ((r>>1)&3).
// Reads (b128, lanes fr=0..15 at rows base+fr, slot fq): bank-group
// (4r + slot) % 8 -> each 4-bank group gets exactly 2 lanes = free.
// glds writes linear (lane*16B): 2 lanes/bank = free. Source slot for lane l
// = (l&3) ^ ((l>>3)&3) -- pure lane function (rule #21: linear dest,
// pre-swizzled source).
// HOF (2 sw x 64 h x {F,G} = 1KB) aliases WD1 rows 176..191: last read kt15
// (pre-HOF barrier), restaged by stage(kt1) which issues after GATE(kt0).
#define XD0 0
#define XD1 8192
#define WD0 16384
#define WD1 28672
#define HOF (WD1 + 12288 - 1024)
#define LDS_BYTES 40960

#define GLDS(src, dst) __builtin_amdgcn_global_load_lds( \
    (const __attribute__((address_space(1))) void*)(src), \
    (__attribute__((address_space(3))) void*)(dst), 16, 0, 0)

__device__ inline float sigm(float v) {
    return __builtin_amdgcn_rcpf(1.f + __expf(-v));
}

// ---------------------------------------------------------------------------
// f32 -> f16 conversion for x and W. 8 elems/thread, 16B stores.
// ---------------------------------------------------------------------------
struct alignas(16) H8 { _Float16 h[8]; };

__global__ __launch_bounds__(256) void cvt_xw(
    const float* __restrict__ x, _Float16* __restrict__ xh, int n8x,
    const float* __restrict__ W, _Float16* __restrict__ Wh, int n8w)
{
    const int t = blockIdx.x * 256 + threadIdx.x;
    const float* src; _Float16* dst; int i;
    if (t < n8x)             { src = x; dst = xh; i = t; }
    else if (t < n8x + n8w)  { src = W; dst = Wh; i = t - n8x; }
    else return;
    const float4* p = (const float4*)(src + (size_t)i * 8);
    const float4 a = p[0], b = p[1];
    H8 o;
    o.h[0] = (_Float16)a.x; o.h[1] = (_Float16)a.y;
    o.h[2] = (_Float16)a.z; o.h[3] = (_Float16)a.w;
    o.h[4] = (_Float16)b.x; o.h[5] = (_Float16)b.y;
    o.h[6] = (_Float16)b.z; o.h[7] = (_Float16)b.w;
    ((H8*)dst)[i] = o;
}

// ---------------------------------------------------------------------------
// Fused GEMM + activations + in-register affine scan (r11 algorithm) at
// BK=32 / 40KB LDS -> 4 blocks/CU for cross-block phase overlap.
// Grid 512 = (b, hs) XCD-affine. Block 256 = 4 waves (sw x gw); wave =
// 64 s x {z,f,o} x 32 h; acc[4][6]. Per kt (x16): GATE{vmcnt;barrier} ->
// STAGE(kt+1) 5 glds -> 10 ds_read_b128 -> lgkm(0) -> 24 MFMA. Scan:
// per-lane run composition + fq Kogge-Stone + HOF handoff (r11-proven).
// ---------------------------------------------------------------------------
__global__ __launch_bounds__(256, 4) void qrnn_fused(
    const _Float16* __restrict__ xh,   // [B*S, K]
    const _Float16* __restrict__ Wh,   // [3H, K]
    const float* __restrict__ bias,    // [3H]
    const float* __restrict__ c0,      // [B, H]
    float* __restrict__ out)           // [B,S,H] ++ [B,H]
{
    extern __shared__ char smem[];

    const int tid  = threadIdx.x;
    const int lane = tid & 63;
    const int wid  = tid >> 6;
    const int gw   = wid & 1;          // h-half (32 h)
    const int sw   = wid >> 1;         // s-half (64 s)
    const int fq   = lane >> 4;
    const int fr   = lane & 15;

    const int bid = blockIdx.x;
    const int b   = (bid & 7) + ((bid >> 7) << 3);
    const int hs  = (bid >> 3) & 15;

    // per-lane h columns (nn = 0,1) and bias
    float bz[2], bff[2], bo[2], cc[2];
    #pragma unroll
    for (int nn = 0; nn < 2; ++nn) {
        const int hcol = hs * HS + gw * 32 + nn * 16 + fr;
        bz[nn]  = bias[hcol];
        bff[nn] = bias[H_ + hcol];
        bo[nn]  = bias[2 * H_ + hcol];
        cc[nn]  = c0[b * H_ + hcol];
    }

    // staging lane constants: chunk = 16 rows x 64B; lane l covers row l>>2,
    // stored slot l&3, source slot (l&3)^((l>>3)&3).
    const int lrow  = lane >> 2;
    const int lsrc  = ((lane & 3) ^ ((lane >> 3) & 3)) << 4;
    const _Float16* xbase = xh + (size_t)(b * S_) * K_;

    auto STAGE = [&](int sc_, int kt_, int xoff, int woff) {
        #pragma unroll
        for (int i = 0; i < 5; ++i) {
            const int cid = wid * 5 + i;           // 0..19 chunks of 1KB
            if (cid < 8) {                         // x rows (s')
                const int r = cid * 16 + lrow;
                const char* src = (const char*)(xbase + (size_t)(sc_ * SC + r) * K_ + kt_ * 32) + lsrc;
                GLDS(src, smem + xoff + cid * 1024);
            } else {                               // W rows (0..191)
                const int r = (cid - 8) * 16 + lrow;
                const int wrow = (r >> 6) * H_ + hs * HS + (r & 63);
                const char* src = (const char*)(Wh + (size_t)wrow * K_ + kt_ * 32) + lsrc;
                GLDS(src, smem + woff + (cid - 8) * 1024);
            }
        }
    };

    // read swizzle: row slot fq stored at fq ^ ((row>>1)&3); row = base16+fr
    // -> (row>>1)&3 = (fr>>1)&3 (base16 multiple of 16).
    const int rdsw = (fq ^ ((fr >> 1) & 3)) << 4;
    int afo[4], bfo[6];
    #pragma unroll
    for (int m = 0; m < 4; ++m)
        afo[m] = (sw * 64 + m * 16 + fr) * 64 + rdsw;
    #pragma unroll
    for (int n = 0; n < 6; ++n)
        bfo[n] = (((n >> 1) * 64 + gw * 32 + (n & 1) * 16 + fr)) * 64 + rdsw;

    STAGE(0, 0, XD0, WD0);

    for (int sc = 0; sc < NSC; ++sc) {
        f32x4 acc[4][6] = {};

        #pragma unroll
        for (int kt = 0; kt < NKT; ++kt) {
            const int cur  = kt & 1;
            const int curx = cur ? XD1 : XD0;
            const int curw = cur ? WD1 : WD0;
            const int nxtx = cur ? XD0 : XD1;
            const int nxtw = cur ? WD0 : WD1;

            // --- GATE: stage(kt) landed on all waves -----------------------
            if (kt == 0 && sc > 0) {
                // 32 backfill stores (newer) may fly; 5 stage loads (older,
                // FIFO) forced complete.
                asm volatile("s_waitcnt vmcnt(32)" ::: "memory");
            } else {
                asm volatile("s_waitcnt vmcnt(0)" ::: "memory");
            }
            __builtin_amdgcn_s_barrier();
            __builtin_amdgcn_sched_barrier(0);

            // prefetch kt+1 (writes nxt buf: all waves' kt-1 reads retired)
            if (kt + 1 < NKT)      STAGE(sc, kt + 1, nxtx, nxtw);
            else if (sc + 1 < NSC) STAGE(sc + 1, 0, nxtx, nxtw);

            f16x8 af[4], bf[6];
            #pragma unroll
            for (int m = 0; m < 4; ++m)
                af[m] = *(const f16x8*)(smem + curx + afo[m]);
            #pragma unroll
            for (int n = 0; n < 6; ++n)
                bf[n] = *(const f16x8*)(smem + curw + bfo[n]);

            asm volatile("s_waitcnt lgkmcnt(0)" ::: "memory");
            __builtin_amdgcn_sched_barrier(0);
            __builtin_amdgcn_s_setprio(1);
            #pragma unroll
            for (int m = 0; m < 4; ++m)
                #pragma unroll
                for (int n = 0; n < 6; ++n)
                    acc[m][n] = __builtin_amdgcn_mfma_f32_16x16x32_f16(
                        af[m], bf[n], acc[m][n], 0, 0, 0);
            __builtin_amdgcn_s_setprio(0);
        }

        // ---- activations + per-lane affine composition ----------------------
        // step: c <- f*c + g, g = (1-f)*z. acc slots after this pass:
        // [m][nn] = g, [m][2+nn] = f, [m][4+nn] = o (all f32).
        float FsS[2][4], GsS[2][4];
        float FP[2], GP[2];
        #pragma unroll
        for (int nn = 0; nn < 2; ++nn) {
            FP[nn] = 1.f; GP[nn] = 0.f;
            #pragma unroll
            for (int m = 0; m < 4; ++m) {
                float Fr = 1.f, Gr = 0.f;
                #pragma unroll
                for (int j = 0; j < 4; ++j) {
                    const float z = 2.f * sigm(2.f * (acc[m][nn][j] + bz[nn])) - 1.f;
                    const float f = sigm(acc[m][2 + nn][j] + bff[nn]);
                    const float g = (1.f - f) * z;
                    acc[m][nn][j]     = g;
                    acc[m][2 + nn][j] = f;
                    acc[m][4 + nn][j] = sigm(acc[m][4 + nn][j] + bo[nn]);
                    Gr = __builtin_fmaf(f, Gr, g);
                    Fr = f * Fr;
                }
                // Kogge-Stone over fq (4 groups of 16 lanes)
                float F1 = __shfl(Fr, lane - 16), G1 = __shfl(Gr, lane - 16);
                if (fq >= 1) { Gr = __builtin_fmaf(Fr, G1, Gr); Fr = Fr * F1; }
                float F2 = __shfl(Fr, lane - 32), G2 = __shfl(Gr, lane - 32);
                if (fq >= 2) { Gr = __builtin_fmaf(Fr, G2, Gr); Fr = Fr * F2; }
                float FE = __shfl(Fr, lane - 16), GE = __shfl(Gr, lane - 16);
                if (fq == 0) { FE = 1.f; GE = 0.f; }
                const float FM = __shfl(Fr, 48 + fr);   // full 16-step map of m
                const float GM = __shfl(Gr, 48 + fr);
                FsS[nn][m] = FE * FP[nn];
                GsS[nn][m] = __builtin_fmaf(FE, GP[nn], GE);
                GP[nn] = __builtin_fmaf(FM, GP[nn], GM);
                FP[nn] = FM * FP[nn];
            }
        }

        // all waves done reading WD1 (kt15 frags) before HOF aliases it
        __builtin_amdgcn_s_barrier();

        // ---- handoff: per-h wave-total (F,G) between sw waves ---------------
        if (fq == 0) {
            #pragma unroll
            for (int nn = 0; nn < 2; ++nn) {
                const int hh = gw * 32 + nn * 16 + fr;
                *(float2*)(smem + HOF + sw * 512 + hh * 8) = make_float2(FP[nn], GP[nn]);
            }
        }
        asm volatile("s_waitcnt lgkmcnt(0)" ::: "memory");
        __builtin_amdgcn_s_barrier();

        // ---- backfill + out stores ------------------------------------------
        #pragma unroll
        for (int nn = 0; nn < 2; ++nn) {
            const int hh = gw * 32 + nn * 16 + fr;
            const float2 m0 = *(const float2*)(smem + HOF + hh * 8);
            const float2 m1 = *(const float2*)(smem + HOF + 512 + hh * 8);
            const float cin = (sw == 0) ? cc[nn]
                                        : __builtin_fmaf(m0.x, cc[nn], m0.y);
            #pragma unroll
            for (int m = 0; m < 4; ++m) {
                float cr = __builtin_fmaf(FsS[nn][m], cin, GsS[nn][m]);
                #pragma unroll
                for (int j = 0; j < 4; ++j) {
                    cr = __builtin_fmaf(acc[m][2 + nn][j], cr, acc[m][nn][j]);
                    const int sg = b * S_ + sc * SC + sw * 64 + m * 16 + fq * 4 + j;
                    out[(size_t)sg * H_ + hs * HS + hh] = acc[m][4 + nn][j] * cr;
                }
            }
            cc[nn] = __builtin_fmaf(m1.x, __builtin_fmaf(m0.x, cc[nn], m0.y), m1.y);
        }
        // HOF reads consumed before stores issue; next GATE barrier precedes
        // any WD1/HOF overwrite (stage(kt1) issues after GATE(kt0)).
    }

    // c_last tail: [1,B,H] appended after [B,S,H]
    if (sw == 0 && fq == 0) {
        #pragma unroll
        for (int nn = 0; nn < 2; ++nn)
            out[(size_t)B_ * S_ * H_ + b * H_ + hs * HS + gw * 32 + nn * 16 + fr] = cc[nn];
    }
}

extern "C" void kernel_launch(void* const* d_in, const int* in_sizes, int n_in,
                              void* d_out, int out_size, void* d_ws, size_t ws_size,
                              hipStream_t stream) {
    const float* x = (const float*)d_in[0];
    const float* h = (const float*)d_in[1];
    const float* W = (const float*)d_in[2];
    const float* b = (const float*)d_in[3];
    float* out = (float*)d_out;

    _Float16* xh = (_Float16*)d_ws;
    _Float16* Wh = xh + (size_t)B_ * S_ * K_;

    (void)hipFuncSetAttribute((const void*)qrnn_fused,
                              hipFuncAttributeMaxDynamicSharedMemorySize, LDS_BYTES);

    const int n8x = B_ * S_ * K_ / 8;   // 1048576
    const int n8w = 3 * H_ * K_ / 8;    // 196608
    cvt_xw<<<(n8x + n8w + 255) / 256, 256, 0, stream>>>(x, xh, n8x, W, Wh, n8w);

    qrnn_fused<<<B_ * (H_ / HS), 256, LDS_BYTES, stream>>>(xh, Wh, b, h, out);
}

// Round 15
// 100.033 us; speedup vs baseline: 3.4352x; 3.4352x over previous
//
#include <hip/hip_runtime.h>
#include <hip/hip_bf16.h>
#include <hip/hip_fp16.h>
#include <stdint.h>

typedef __attribute__((ext_vector_type(8))) _Float16 f16x8;
typedef __attribute__((ext_vector_type(4))) float f32x4;

#define B_  32
#define S_  512
#define K_  512
#define H_  1024
#define HS  16           // h-cols per block
#define SC  256          // s-rows per chunk
#define NKT 16           // K_/32
#define NSC 2            // S_/SC

// LDS: W resident [48 rows][1KB full-K] @0 (48KB, staged ONCE) |
//      x dbuf 2x16KB @49152/@65536. Total 80KB -> 2 blocks/CU.
// W swizzle (1KB rows): stored slot j holds logical slot j^row; read logical
// q at stored q^row. Lanes (fq,fr) read slot (kt*4+fq)^(n*16+fr): 16 fr ->
// 16 distinct slots mod 32 -> 2 lanes/bank = free. Stage: lane l writes
// stored slot l (linear dest), src byte (l^row)*16 -- pure lane fn (rule #21).
// x swizzle (64B rows, r14-proven 0-conflict): stored slot = logical ^
// ((row>>1)&3); read slot (fq ^ ((fr>>1)&3)); stage src slot (l&3)^((l>>3)&3).
// HOF (4 waves x 16 h x {F,G} = 512B) aliases XD1 tail: XD1 dead between the
// post-kt15 barrier and stage(kt1) (which issues after GATE(kt0), by which
// time backfill consumed HOF).
#define WS_  0
#define XD0  49152
#define XD1  65536
#define HOF  (XD1 + 16384 - 512)
#define LDS_BYTES 81920

#define GLDS(src, dst) __builtin_amdgcn_global_load_lds( \
    (const __attribute__((address_space(1))) void*)(src), \
    (__attribute__((address_space(3))) void*)(dst), 16, 0, 0)

__device__ inline float sigm(float v) {
    return __builtin_amdgcn_rcpf(1.f + __expf(-v));
}

// ---------------------------------------------------------------------------
// f32 -> f16 conversion for x and W. 8 elems/thread, 16B stores.
// ---------------------------------------------------------------------------
struct alignas(16) H8 { _Float16 h[8]; };

__global__ __launch_bounds__(256) void cvt_xw(
    const float* __restrict__ x, _Float16* __restrict__ xh, int n8x,
    const float* __restrict__ W, _Float16* __restrict__ Wh, int n8w)
{
    const int t = blockIdx.x * 256 + threadIdx.x;
    const float* src; _Float16* dst; int i;
    if (t < n8x)             { src = x; dst = xh; i = t; }
    else if (t < n8x + n8w)  { src = W; dst = Wh; i = t - n8x; }
    else return;
    const float4* p = (const float4*)(src + (size_t)i * 8);
    const float4 a = p[0], b = p[1];
    H8 o;
    o.h[0] = (_Float16)a.x; o.h[1] = (_Float16)a.y;
    o.h[2] = (_Float16)a.z; o.h[3] = (_Float16)a.w;
    o.h[4] = (_Float16)b.x; o.h[5] = (_Float16)b.y;
    o.h[6] = (_Float16)b.z; o.h[7] = (_Float16)b.w;
    ((H8*)dst)[i] = o;
}

// ---------------------------------------------------------------------------
// Fused GEMM + activations + in-register affine scan, W-resident layout.
// Grid 2048 = (b, hs16) XCD-affine (4 b's/XCD -> x slice 2MB L2-resident).
// Block 256 = 4 waves, wave = 64 s-rows x 48 gate-cols (all 3 gates of the
// block's 16 h-cols); acc[4][3]; one h-col per lane (h = hs*16 + fr).
// dupA=1 (each x-frag read once), dupB=4; W staged once for all 32 kt.
// Per kt (BK=32): GATE{vmcnt;barrier} -> STAGEX(kt+1) 4 glds -> 4 af + 3 bf
// ds_reads -> lgkm(0) -> 12 MFMA. One barrier per kt.
// Scan: per-lane 4-step runs (m=0..3), fq Kogge-Stone, 4-wave chain via HOF.
// ---------------------------------------------------------------------------
__global__ __launch_bounds__(256, 2) void qrnn_fused(
    const _Float16* __restrict__ xh,   // [B*S, K]
    const _Float16* __restrict__ Wh,   // [3H, K]
    const float* __restrict__ bias,    // [3H]
    const float* __restrict__ c0,      // [B, H]
    float* __restrict__ out)           // [B,S,H] ++ [B,H]
{
    extern __shared__ char smem[];

    const int tid  = threadIdx.x;
    const int lane = tid & 63;
    const int wid  = tid >> 6;         // s-quarter of the chunk (64 rows)
    const int fq   = lane >> 4;
    const int fr   = lane & 15;

    const int bid = blockIdx.x;
    const int b   = (bid & 7) + 8 * ((bid >> 3) & 3);
    const int hs  = bid >> 5;          // 0..63

    const int hcol = hs * HS + fr;
    const float bz  = bias[hcol];
    const float bff = bias[H_ + hcol];
    const float bo  = bias[2 * H_ + hcol];
    float cc = c0[b * H_ + hcol];

    const _Float16* xbase = xh + (size_t)(b * S_) * K_;

    // ---- W: stage once, full K, swizzled rows ------------------------------
    {
        #pragma unroll
        for (int i = 0; i < 12; ++i) {
            const int r = wid * 12 + i;              // 0..47 (gate*16 + rr)
            const int wrow = (r >> 4) * H_ + hs * HS + (r & 15);
            const char* src = (const char*)(Wh + (size_t)wrow * K_) + ((lane ^ r) << 4);
            GLDS(src, smem + WS_ + r * 1024);
        }
    }

    // x staging lane constants (r14-proven 64B-row swizzle)
    const int lrow = lane >> 2;
    const int lsrc = ((lane & 3) ^ ((lane >> 3) & 3)) << 4;

    auto STAGEX = [&](int sc_, int kt_, int xoff) {
        #pragma unroll
        for (int i = 0; i < 4; ++i) {
            const int cid = wid * 4 + i;             // 0..15 chunks of 1KB
            const char* src = (const char*)(xbase + (size_t)(sc_ * SC + cid * 16 + lrow) * K_
                                            + kt_ * 32) + lsrc;
            GLDS(src, smem + xoff + cid * 1024);
        }
    };

    // read-offset constants
    const int rdswx = (fq ^ ((fr >> 1) & 3)) << 4;   // x: 64B rows
    int afo[4];
    #pragma unroll
    for (int m = 0; m < 4; ++m)
        afo[m] = (wid * 64 + m * 16 + fr) * 64 + rdswx;

    STAGEX(0, 0, XD0);
    asm volatile("s_waitcnt vmcnt(0)" ::: "memory");   // W + x(0,0) landed

    for (int sc = 0; sc < NSC; ++sc) {
        f32x4 acc[4][3] = {};

        #pragma unroll
        for (int kt = 0; kt < NKT; ++kt) {
            const int curx = (kt & 1) ? XD1 : XD0;
            const int nxtx = (kt & 1) ? XD0 : XD1;

            // --- GATE: x(kt) landed on all waves ---------------------------
            if (kt == 0 && sc > 0) {
                // 16 backfill stores (newer) fly; 4 x-glds (older) complete.
                asm volatile("s_waitcnt vmcnt(16)" ::: "memory");
            } else {
                asm volatile("s_waitcnt vmcnt(0)" ::: "memory");
            }
            __builtin_amdgcn_s_barrier();

            if (kt + 1 < NKT)      STAGEX(sc, kt + 1, nxtx);
            else if (sc + 1 < NSC) STAGEX(sc + 1, 0, nxtx);

            f16x8 af[4], bf[3];
            #pragma unroll
            for (int m = 0; m < 4; ++m)
                af[m] = *(const f16x8*)(smem + curx + afo[m]);
            #pragma unroll
            for (int n = 0; n < 3; ++n) {
                const int row = n * 16 + fr;
                const int slot = (kt * 4 + fq) ^ row;
                bf[n] = *(const f16x8*)(smem + WS_ + row * 1024 + slot * 16);
            }

            asm volatile("s_waitcnt lgkmcnt(0)" ::: "memory");
            __builtin_amdgcn_sched_barrier(0);
            __builtin_amdgcn_s_setprio(1);
            #pragma unroll
            for (int m = 0; m < 4; ++m)
                #pragma unroll
                for (int n = 0; n < 3; ++n)
                    acc[m][n] = __builtin_amdgcn_mfma_f32_16x16x32_f16(
                        af[m], bf[n], acc[m][n], 0, 0, 0);
            __builtin_amdgcn_s_setprio(0);
        }

        // all waves' kt15 XD1-reads retired before HOF aliases the XD1 tail
        __builtin_amdgcn_s_barrier();

        // ---- activations + per-lane affine composition ----------------------
        // step: c <- f*c + g, g = (1-f)*z. acc: [m][0]=g, [m][1]=f, [m][2]=o.
        float FsS[4], GsS[4];
        float FP = 1.f, GP = 0.f;
        #pragma unroll
        for (int m = 0; m < 4; ++m) {
            float Fr = 1.f, Gr = 0.f;
            #pragma unroll
            for (int j = 0; j < 4; ++j) {
                const float z = 2.f * sigm(2.f * (acc[m][0][j] + bz)) - 1.f;
                const float f = sigm(acc[m][1][j] + bff);
                const float g = (1.f - f) * z;
                acc[m][0][j] = g;
                acc[m][1][j] = f;
                acc[m][2][j] = sigm(acc[m][2][j] + bo);
                Gr = __builtin_fmaf(f, Gr, g);
                Fr = f * Fr;
            }
            // Kogge-Stone over fq (4 groups of 16 lanes)
            float F1 = __shfl(Fr, lane - 16), G1 = __shfl(Gr, lane - 16);
            if (fq >= 1) { Gr = __builtin_fmaf(Fr, G1, Gr); Fr = Fr * F1; }
            float F2 = __shfl(Fr, lane - 32), G2 = __shfl(Gr, lane - 32);
            if (fq >= 2) { Gr = __builtin_fmaf(Fr, G2, Gr); Fr = Fr * F2; }
            float FE = __shfl(Fr, lane - 16), GE = __shfl(Gr, lane - 16);
            if (fq == 0) { FE = 1.f; GE = 0.f; }
            const float FM = __shfl(Fr, 48 + fr);   // 16-step map of m-block
            const float GM = __shfl(Gr, 48 + fr);
            FsS[m] = FE * FP;
            GsS[m] = __builtin_fmaf(FE, GP, GE);
            GP = __builtin_fmaf(FM, GP, GM);
            FP = FM * FP;
        }

        // ---- 4-wave chain: per-h wave totals via HOF ------------------------
        if (fq == 0)
            *(float2*)(smem + HOF + (wid * 16 + fr) * 8) = make_float2(FP, GP);
        asm volatile("s_waitcnt lgkmcnt(0)" ::: "memory");
        __builtin_amdgcn_s_barrier();

        float cin = cc, crun = cc;
        #pragma unroll
        for (int v = 0; v < 4; ++v) {
            const float2 t = *(const float2*)(smem + HOF + (v * 16 + fr) * 8);
            if (v == wid) cin = crun;
            crun = __builtin_fmaf(t.x, crun, t.y);
        }
        cc = crun;   // chunk-exit state (identical in all waves)

        // ---- backfill + out stores ------------------------------------------
        #pragma unroll
        for (int m = 0; m < 4; ++m) {
            float cr = __builtin_fmaf(FsS[m], cin, GsS[m]);
            float* orow = out + (size_t)(b * S_ + sc * SC + wid * 64 + m * 16 + fq * 4) * H_ + hcol;
            #pragma unroll
            for (int j = 0; j < 4; ++j) {
                cr = __builtin_fmaf(acc[m][1][j], cr, acc[m][0][j]);
                orow[(size_t)j * H_] = acc[m][2][j] * cr;
            }
        }
        // HOF consumed before next GATE; stage(kt1) (XD1 overwrite) issues
        // only after GATE(kt0).
    }

    // c_last tail: [1,B,H] appended after [B,S,H]
    if (wid == 0 && fq == 0)
        out[(size_t)B_ * S_ * H_ + b * H_ + hcol] = cc;
}

extern "C" void kernel_launch(void* const* d_in, const int* in_sizes, int n_in,
                              void* d_out, int out_size, void* d_ws, size_t ws_size,
                              hipStream_t stream) {
    const float* x = (const float*)d_in[0];
    const float* h = (const float*)d_in[1];
    const float* W = (const float*)d_in[2];
    const float* b = (const float*)d_in[3];
    float* out = (float*)d_out;

    _Float16* xh = (_Float16*)d_ws;
    _Float16* Wh = xh + (size_t)B_ * S_ * K_;

    (void)hipFuncSetAttribute((const void*)qrnn_fused,
                              hipFuncAttributeMaxDynamicSharedMemorySize, LDS_BYTES);

    const int n8x = B_ * S_ * K_ / 8;   // 1048576
    const int n8w = 3 * H_ * K_ / 8;    // 196608
    cvt_xw<<<(n8x + n8w + 255) / 256, 256, 0, stream>>>(x, xh, n8x, W, Wh, n8w);

    qrnn_fused<<<B_ * (H_ / HS), 256, LDS_BYTES, stream>>>(xh, Wh, b, h, out);
}

// Round 16
// 72.133 us; speedup vs baseline: 4.7638x; 1.3868x over previous
//
#include <hip/hip_runtime.h>
#include <hip/hip_bf16.h>
#include <hip/hip_fp16.h>
#include <stdint.h>

typedef __attribute__((ext_vector_type(8))) _Float16 f16x8;
typedef __attribute__((ext_vector_type(4))) float f32x4;

#define B_  32
#define S_  512
#define K_  512
#define H_  1024
#define HS  64           // h-cols per block
#define SC  128          // s-rows per chunk
#define NKT 8            // K_/64
#define NSC 4            // S_/SC

// LDS: x dbuf 2x16K | W dbuf 2x24K = 80KB -> 2 blocks/CU.
// handoff (2 sw x 64 h x {F,G} f32 = 1KB) aliases WD1 rows 184..191 (r11-
// proven hazard window: dead between pre-HOF barrier and kt0's stage(kt1)).
#define XD0 0
#define XD1 16384
#define WD0 32768
#define WD1 57344
#define HOF (WD1 + 24576 - 1024)
#define LDS_BYTES 81920

#define GLDS(src, dst) __builtin_amdgcn_global_load_lds( \
    (const __attribute__((address_space(1))) void*)(src), \
    (__attribute__((address_space(3))) void*)(dst), 16, 0, 0)

__device__ inline float sigm(float v) {
    return __builtin_amdgcn_rcpf(1.f + __expf(-v));
}

// ---------------------------------------------------------------------------
// f32 -> f16 conversion for x and W. 8 elems/thread, 16B stores.
// ---------------------------------------------------------------------------
struct alignas(16) H8 { _Float16 h[8]; };

__global__ __launch_bounds__(256) void cvt_xw(
    const float* __restrict__ x, _Float16* __restrict__ xh, int n8x,
    const float* __restrict__ W, _Float16* __restrict__ Wh, int n8w)
{
    const int t = blockIdx.x * 256 + threadIdx.x;
    const float* src; _Float16* dst; int i;
    if (t < n8x)             { src = x; dst = xh; i = t; }
    else if (t < n8x + n8w)  { src = W; dst = Wh; i = t - n8x; }
    else return;
    const float4* p = (const float4*)(src + (size_t)i * 8);
    const float4 a = p[0], b = p[1];
    H8 o;
    o.h[0] = (_Float16)a.x; o.h[1] = (_Float16)a.y;
    o.h[2] = (_Float16)a.z; o.h[3] = (_Float16)a.w;
    o.h[4] = (_Float16)b.x; o.h[5] = (_Float16)b.y;
    o.h[6] = (_Float16)b.z; o.h[7] = (_Float16)b.w;
    ((H8*)dst)[i] = o;
}

// ---------------------------------------------------------------------------
// Fused GEMM + activations + in-register affine scan (r11 structure).
// r16 change: ALL loop addressing precomputed.
//  - staging: voff[10] = 32-bit absolute per-lane offsets from xh (b, row,
//    swizzle, and Wh-xh baked in; x entries bumped +SC*K*2 per chunk);
//    per-glds address = xh(saddr) + voff(voffset) + kt*128(imm). ldstA/B[10]
//    are per-parity LDS dests.
//  - frag reads: afoK[2][4]/bfoK[2][6] swizzled byte offsets (ks baked in);
//    read = smem + buffer-const + afoK  ->  ds_read_b128 vaddr + imm.
// Per kt: GATE{vmcnt(32|0); barrier} -> 2 sub-phases {10 ds_read + 5 glds ->
// barrier -> lgkm(0) -> 24 MFMA -> barrier}. Epilogue/HOF/backfill = r11.
// ---------------------------------------------------------------------------
__global__ __launch_bounds__(256, 2) void qrnn_fused(
    const _Float16* __restrict__ xh,   // [B*S, K]  (Wh = xh + B*S*K)
    const _Float16* __restrict__ Wh,   // [3H, K]
    const float* __restrict__ bias,    // [3H]
    const float* __restrict__ c0,      // [B, H]
    float* __restrict__ out)           // [B,S,H] ++ [B,H]
{
    extern __shared__ char smem[];

    const int tid  = threadIdx.x;
    const int lane = tid & 63;
    const int wid  = tid >> 6;
    const int gw   = wid & 1;          // h-half (32 h)
    const int sw   = wid >> 1;         // s-half (64 s)
    const int fq   = lane >> 4;
    const int fr   = lane & 15;

    const int bid = blockIdx.x;
    const int b   = (bid & 7) + ((bid >> 7) << 3);
    const int hs  = (bid >> 3) & 15;

    // per-lane h columns (nn = 0,1) and bias
    float bz[2], bff[2], bo[2], cc[2];
    #pragma unroll
    for (int nn = 0; nn < 2; ++nn) {
        const int hcol = hs * HS + gw * 32 + nn * 16 + fr;
        bz[nn]  = bias[hcol];
        bff[nn] = bias[H_ + hcol];
        bo[nn]  = bias[2 * H_ + hcol];
        cc[nn]  = c0[b * H_ + hcol];
    }

    const int srow  = lane >> 3;
    const int scolb = (((lane & 7) ^ (lane >> 3)) << 4);

    // ---- precomputed staging offsets (32-bit, absolute from xh) ------------
    uint32_t voff[10];
    int ldstA[10], ldstB[10];
    #pragma unroll
    for (int i = 0; i < 10; ++i) {
        const int cid = wid * 10 + i;
        if (cid < 16) {                // x chunk: rows of this b's x slab
            const int r = cid * 8 + srow;
            voff[i]  = (uint32_t)((b * S_ + r) * (K_ * 2)) + (uint32_t)scolb;
            ldstA[i] = XD0 + cid * 1024;
            ldstB[i] = XD1 + cid * 1024;
        } else {                       // W chunk (Wh = xh + 32MB)
            const int r = (cid - 16) * 8 + srow;
            const int wrow = (r >> 6) * H_ + hs * HS + (r & 63);
            voff[i]  = (uint32_t)(B_ * S_ * K_ * 2) + (uint32_t)(wrow * (K_ * 2)) + (uint32_t)scolb;
            ldstA[i] = WD0 + (cid - 16) * 1024;
            ldstB[i] = WD1 + (cid - 16) * 1024;
        }
    }

    // half-stage: pB selects XD1/WD1 dests; ktimm is a compile-time constant
    auto STAGEH = [&](int ktimm, bool pB, int half) {
        #pragma unroll
        for (int i = half * 5; i < half * 5 + 5; ++i) {
            GLDS((const char*)xh + ktimm * 128 + (size_t)voff[i],
                 smem + (pB ? ldstB[i] : ldstA[i]));
        }
    };

    // ---- precomputed frag read offsets (swizzle + ks baked in) -------------
    int afoK[2][4], bfoK[2][6];
    #pragma unroll
    for (int ks = 0; ks < 2; ++ks) {
        #pragma unroll
        for (int m = 0; m < 4; ++m) {
            const int row = sw * 64 + m * 16 + fr;
            const int kb  = ks * 64 + fq * 16;
            afoK[ks][m] = row * 128 + (kb ^ ((row & 7) << 4));
        }
        #pragma unroll
        for (int n = 0; n < 6; ++n) {
            const int row = (n >> 1) * 64 + gw * 32 + (n & 1) * 16 + fr;
            const int kb  = ks * 64 + fq * 16;
            bfoK[ks][n] = row * 128 + (kb ^ ((row & 7) << 4));
        }
    }

    STAGEH(0, false, 0);
    STAGEH(0, false, 1);
    asm volatile("s_waitcnt vmcnt(0)" ::: "memory");   // drain prologue stage

    for (int sc = 0; sc < NSC; ++sc) {
        f32x4 acc[4][6] = {};

        #pragma unroll
        for (int kt = 0; kt < NKT; ++kt) {
            const int cur  = kt & 1;
            const int curx = cur ? XD1 : XD0;
            const int curw = cur ? WD1 : WD0;
            const bool nxtB = !cur;    // stage target parity

            // --- GATE: cur buffer landed on all waves ----------------------
            if (kt == 0) {
                // 32 backfill stores (newer) may fly; 10 stage loads (older,
                // FIFO) forced complete. (sc==0: nothing outstanding.)
                asm volatile("s_waitcnt vmcnt(32)" ::: "memory");
            } else {
                asm volatile("s_waitcnt vmcnt(0)" ::: "memory");
            }
            __builtin_amdgcn_s_barrier();
            __builtin_amdgcn_sched_barrier(0);

            // bump x staging offsets to next chunk before kt7's prestage
            if (kt == NKT - 1 && sc + 1 < NSC) {
                #pragma unroll
                for (int i = 0; i < 10; ++i)
                    if (wid * 10 + i < 16) voff[i] += SC * K_ * 2;
            }

            #pragma unroll
            for (int ks = 0; ks < 2; ++ks) {
                f16x8 af[4], bf[6];
                #pragma unroll
                for (int m = 0; m < 4; ++m)
                    af[m] = *(const f16x8*)(smem + curx + afoK[ks][m]);
                #pragma unroll
                for (int n = 0; n < 6; ++n)
                    bf[n] = *(const f16x8*)(smem + curw + bfoK[ks][n]);

                // half-stage for kt+1 issues under this sub-phase
                if (kt + 1 < NKT)      STAGEH(kt + 1, nxtB, ks);
                else if (sc + 1 < NSC) STAGEH(0, nxtB, ks);

                __builtin_amdgcn_s_barrier();
                asm volatile("s_waitcnt lgkmcnt(0)" ::: "memory");
                __builtin_amdgcn_sched_barrier(0);
                __builtin_amdgcn_s_setprio(1);
                #pragma unroll
                for (int m = 0; m < 4; ++m)
                    #pragma unroll
                    for (int n = 0; n < 6; ++n)
                        acc[m][n] = __builtin_amdgcn_mfma_f32_16x16x32_f16(
                            af[m], bf[n], acc[m][n], 0, 0, 0);
                __builtin_amdgcn_s_setprio(0);
                if (ks == 0) __builtin_amdgcn_s_barrier();
                // ks==1 trailing barrier = next kt's GATE barrier
            }
        }

        // ---- activations + per-lane affine composition (register-only) ------
        // step: c <- f*c + g, g = (1-f)*z. acc slots after this pass:
        // [m][nn] = g, [m][2+nn] = f, [m][4+nn] = o (all f32).
        float FsS[2][4], GsS[2][4];   // chunk-start -> run(m)-start coeffs
        float FP[2], GP[2];           // wave-total map (exclusive prefix over m)
        #pragma unroll
        for (int nn = 0; nn < 2; ++nn) {
            FP[nn] = 1.f; GP[nn] = 0.f;
            #pragma unroll
            for (int m = 0; m < 4; ++m) {
                float Fr = 1.f, Gr = 0.f;
                #pragma unroll
                for (int j = 0; j < 4; ++j) {
                    const float z = 2.f * sigm(2.f * (acc[m][nn][j] + bz[nn])) - 1.f;
                    const float f = sigm(acc[m][2 + nn][j] + bff[nn]);
                    const float g = (1.f - f) * z;
                    acc[m][nn][j]     = g;
                    acc[m][2 + nn][j] = f;
                    acc[m][4 + nn][j] = sigm(acc[m][4 + nn][j] + bo[nn]);
                    Gr = __builtin_fmaf(f, Gr, g);
                    Fr = f * Fr;
                }
                // Kogge-Stone over fq (4 groups of 16 lanes)
                float F1 = __shfl(Fr, lane - 16), G1 = __shfl(Gr, lane - 16);
                if (fq >= 1) { Gr = __builtin_fmaf(Fr, G1, Gr); Fr = Fr * F1; }
                float F2 = __shfl(Fr, lane - 32), G2 = __shfl(Gr, lane - 32);
                if (fq >= 2) { Gr = __builtin_fmaf(Fr, G2, Gr); Fr = Fr * F2; }
                float FE = __shfl(Fr, lane - 16), GE = __shfl(Gr, lane - 16);
                if (fq == 0) { FE = 1.f; GE = 0.f; }
                const float FM = __shfl(Fr, 48 + fr);   // full 16-step map of m
                const float GM = __shfl(Gr, 48 + fr);
                FsS[nn][m] = FE * FP[nn];
                GsS[nn][m] = __builtin_fmaf(FE, GP[nn], GE);
                GP[nn] = __builtin_fmaf(FM, GP[nn], GM);
                FP[nn] = FM * FP[nn];
            }
        }

        // all waves done reading WD1 (kt7 frags) before HOF write aliases it
        __builtin_amdgcn_s_barrier();

        // ---- handoff: per-h wave-total (F,G) between sw waves ---------------
        if (fq == 0) {
            #pragma unroll
            for (int nn = 0; nn < 2; ++nn) {
                const int hh = gw * 32 + nn * 16 + fr;
                *(float2*)(smem + HOF + sw * 512 + hh * 8) = make_float2(FP[nn], GP[nn]);
            }
        }
        asm volatile("s_waitcnt lgkmcnt(0)" ::: "memory");
        __builtin_amdgcn_s_barrier();

        // ---- backfill + out stores ------------------------------------------
        #pragma unroll
        for (int nn = 0; nn < 2; ++nn) {
            const int hh = gw * 32 + nn * 16 + fr;
            const float2 m0 = *(const float2*)(smem + HOF + hh * 8);
            const float2 m1 = *(const float2*)(smem + HOF + 512 + hh * 8);
            const float cin = (sw == 0) ? cc[nn]
                                        : __builtin_fmaf(m0.x, cc[nn], m0.y);
            #pragma unroll
            for (int m = 0; m < 4; ++m) {
                float cr = __builtin_fmaf(FsS[nn][m], cin, GsS[nn][m]);
                #pragma unroll
                for (int j = 0; j < 4; ++j) {
                    cr = __builtin_fmaf(acc[m][2 + nn][j], cr, acc[m][nn][j]);
                    const int sg = b * S_ + sc * SC + sw * 64 + m * 16 + fq * 4 + j;
                    out[(size_t)sg * H_ + hs * HS + hh] = acc[m][4 + nn][j] * cr;
                }
            }
            cc[nn] = __builtin_fmaf(m1.x, __builtin_fmaf(m0.x, cc[nn], m0.y), m1.y);
        }
        // HOF reads consumed before these stores issue; next GATE barrier
        // precedes any WD1/HOF overwrite.
    }

    // c_last tail: [1,B,H] appended after [B,S,H]
    if (sw == 0 && fq == 0) {
        #pragma unroll
        for (int nn = 0; nn < 2; ++nn)
            out[(size_t)B_ * S_ * H_ + b * H_ + hs * HS + gw * 32 + nn * 16 + fr] = cc[nn];
    }
}

extern "C" void kernel_launch(void* const* d_in, const int* in_sizes, int n_in,
                              void* d_out, int out_size, void* d_ws, size_t ws_size,
                              hipStream_t stream) {
    const float* x = (const float*)d_in[0];
    const float* h = (const float*)d_in[1];
    const float* W = (const float*)d_in[2];
    const float* b = (const float*)d_in[3];
    float* out = (float*)d_out;

    _Float16* xh = (_Float16*)d_ws;
    _Float16* Wh = xh + (size_t)B_ * S_ * K_;   // contiguous: Wh - xh = 32MB

    (void)hipFuncSetAttribute((const void*)qrnn_fused,
                              hipFuncAttributeMaxDynamicSharedMemorySize, LDS_BYTES);

    const int n8x = B_ * S_ * K_ / 8;   // 1048576
    const int n8w = 3 * H_ * K_ / 8;    // 196608
    cvt_xw<<<(n8x + n8w + 255) / 256, 256, 0, stream>>>(x, xh, n8x, W, Wh, n8w);

    qrnn_fused<<<B_ * (H_ / HS), 256, LDS_BYTES, stream>>>(xh, Wh, b, h, out);
}